// Round 7
// baseline (241.242 us; speedup 1.0000x reference)
//
#include <hip/hip_runtime.h>
#include <math.h>

#define D_DIM 256
#define HW 16384
#define C 19
#define N_PX 131072
#define EPS 1e-8f

#define S_SC  1048576.0f       // 2^20 fixed point for class sums
#define IS_S  (1.0f/1048576.0f)
#define U_SC  16777216.0f      // 2^24 fixed point for unit-vector sums
#define IS_U  (1.0f/16777216.0f)

// ws layout in 4-byte words
#define OFF_S     0        // int[4864]     class sums Σf (fixed-point)
#define OFF_U     4864     // int[4864]     class unit sums Σf/||f|| (fixed-point)
#define OFF_CNT   9728     // int[19]       class counts
#define WS_ZERO   9747
#define OFF_IO    9760     // float[131072] U_SC/||f_px||  (plain stores, no zero needed)
#define OFF_PART  141312   // int[1024][2432] per-(slice,chunk) partials (10 MB), 16B-aligned
#define PROW      2432     // words per partial row: S(19*64) | U(19*64)

// ---------- k0: zero final accumulators only ----------
__global__ void k0_zero(int* __restrict__ ws) {
    int i = blockIdx.x * blockDim.x + threadIdx.x;
    if (i < WS_ZERO) ws[i] = 0;
}

// ---------- kA: per-pixel U_SC/||f|| — pure register stream ----------
// grid 512: block = 256 px. 256 thr = 64 px-quads (q, float4) x 4 d-quarters (dq, 64 d).
// No atomics anywhere; LDS only for the 4-way d-combine at the end.
__global__ __launch_bounds__(256) void kA_nf(const float* __restrict__ in,
                                             int* __restrict__ wsi) {
    __shared__ __align__(16) float4 s_nf[64 * 4];   // [quad][dq]
    const int tid = threadIdx.x;
    const int q   = tid & 63;
    const int dq  = tid >> 6;

    const int px0 = blockIdx.x << 8;          // 256 px per block (64 blocks/image)
    const int b   = px0 >> 14;
    const float* base = in + (((size_t)(b * D_DIM + (dq << 6))) << 14)
                           + (px0 & (HW - 1)) + (q << 2);

    float4 nf = {0.f, 0.f, 0.f, 0.f};
    #pragma unroll 16
    for (int d = 0; d < 64; ++d) {
        float4 v = *(const float4*)(base + ((size_t)d << 14));
        nf.x += v.x * v.x; nf.y += v.y * v.y;
        nf.z += v.z * v.z; nf.w += v.w * v.w;
    }
    s_nf[(q << 2) + dq] = nf;
    __syncthreads();

    if (tid < 64) {                            // one wave finishes 256 px
        float4 a = s_nf[tid << 2], b2 = s_nf[(tid << 2) + 1],
               c = s_nf[(tid << 2) + 2], d2 = s_nf[(tid << 2) + 3];
        float4 t;
        t.x = a.x + b2.x + c.x + d2.x;
        t.y = a.y + b2.y + c.y + d2.y;
        t.z = a.z + b2.z + c.z + d2.z;
        t.w = a.w + b2.w + c.w + d2.w;
        float4 io;
        io.x = t.x > 0.f ? U_SC * rsqrtf(t.x) : 0.f;
        io.y = t.y > 0.f ? U_SC * rsqrtf(t.y) : 0.f;
        io.z = t.z > 0.f ? U_SC * rsqrtf(t.z) : 0.f;
        io.w = t.w > 0.f ? U_SC * rsqrtf(t.w) : 0.f;
        *(float4*)((float*)wsi + OFF_IO + px0 + (tid << 2)) = io;
    }
}

// ---------- kB: S + U class accumulation, 64-d slices, 10 KB LDS ----------
// grid (256, 4): x = 512-px chunk, y = 64-d slice. 256 thr = 128 quads x 2 d-halves (32 d).
__global__ __launch_bounds__(256) void kB_accu(const float* __restrict__ in,
                                               const int* __restrict__ tgt,
                                               int* __restrict__ wsi) {
    __shared__ int sS[C * 65];    // addr la*65+ds: distinct labels -> distinct banks
    __shared__ int sU[C * 65];
    __shared__ int s_cnt[C];
    const int tid = threadIdx.x;
    const int q   = tid & 127;
    const int dh  = tid >> 7;
    for (int i = tid; i < C * 65; i += 256) { sS[i] = 0; sU[i] = 0; }
    if (tid < C) s_cnt[tid] = 0;
    __syncthreads();

    const int px0   = blockIdx.x << 9;        // 512 px per chunk (32 chunks/image)
    const int slice = blockIdx.y;
    const int b     = px0 >> 14;
    const int p     = px0 + (q << 2);

    const int4   lab = *(const int4*)(tgt + p);
    const float4 io  = *(const float4*)((const float*)wsi + OFF_IO + p);
    if (slice == 0 && dh == 0) {              // 128 threads count 512 px
        atomicAdd(&s_cnt[lab.x], 1); atomicAdd(&s_cnt[lab.y], 1);
        atomicAdd(&s_cnt[lab.z], 1); atomicAdd(&s_cnt[lab.w], 1);
    }

    const float* base = in
        + (((size_t)(b * D_DIM + (slice << 6) + (dh << 5))) << 14)
        + (px0 & (HW - 1)) + (q << 2);

    #pragma unroll 4
    for (int d = 0; d < 32; ++d) {
        float4 v = *(const float4*)(base + ((size_t)d << 14));
        const int ds = (dh << 5) + d;         // d within slice, uniform across lanes
        atomicAdd(&sS[lab.x * 65 + ds], __float2int_rn(v.x * S_SC));
        atomicAdd(&sS[lab.y * 65 + ds], __float2int_rn(v.y * S_SC));
        atomicAdd(&sS[lab.z * 65 + ds], __float2int_rn(v.z * S_SC));
        atomicAdd(&sS[lab.w * 65 + ds], __float2int_rn(v.w * S_SC));
        atomicAdd(&sU[lab.x * 65 + ds], __float2int_rn(v.x * io.x));
        atomicAdd(&sU[lab.y * 65 + ds], __float2int_rn(v.y * io.y));
        atomicAdd(&sU[lab.z * 65 + ds], __float2int_rn(v.z * io.z));
        atomicAdd(&sU[lab.w * 65 + ds], __float2int_rn(v.w * io.w));
    }
    __syncthreads();

    // plain coalesced partial-row writeout
    int* __restrict__ row = wsi + OFF_PART + (size_t)((slice << 8) + blockIdx.x) * PROW;
    for (int i = tid; i < C * 64; i += 256) {
        int c = i >> 6, ds = i & 63;
        row[i]            = sS[c * 65 + ds];
        row[C * 64 + i]   = sU[c * 65 + ds];
    }
    if (slice == 0 && tid < C) atomicAdd(&wsi[OFF_CNT + tid], s_cnt[tid]);
}

// ---------- k1b: reduce 1024 partial rows -> final S/U ----------
// grid (3, 32): x covers 608 int4 cols, y = slice(4) x row-group(8 of 32 rows).
__global__ __launch_bounds__(256) void k1b_reduce(int* __restrict__ wsi) {
    const int c4 = blockIdx.x * 256 + threadIdx.x;
    if (c4 >= PROW / 4) return;
    const int slice = blockIdx.y >> 3;
    const int rg    = blockIdx.y & 7;
    const int4* base = (const int4*)(wsi + OFF_PART)
                     + ((size_t)(slice << 8) + (rg << 5)) * (PROW / 4) + c4;
    int4 acc = {0, 0, 0, 0};
    #pragma unroll
    for (int r = 0; r < 32; ++r) {
        int4 v = base[(size_t)r * (PROW / 4)];
        acc.x += v.x; acc.y += v.y; acc.z += v.z; acc.w += v.w;
    }
    const int isU = c4 >= 304;
    const int j   = c4 - (isU ? 304 : 0);
    const int c   = j >> 4;
    const int d4  = j & 15;
    int* dst = wsi + (isU ? OFF_U : OFF_S) + c * D_DIM + (slice << 6) + (d4 << 2);
    atomicAdd(dst + 0, acc.x);
    atomicAdd(dst + 1, acc.y);
    atomicAdd(dst + 2, acc.z);
    atomicAdd(dst + 3, acc.w);
}

// ---------- k2: centers, norms, Gram/diff, sim, final (1 block; validated) ----------
__global__ __launch_bounds__(512) void k2_final(const int* __restrict__ wsi,
                                                float* __restrict__ out) {
    __shared__ __align__(16) float s_cen[C * 260];
    __shared__ __align__(16) float s_u[C * 260];
    __shared__ float s_nc[C];
    __shared__ float s_cntf[C];
    __shared__ float s_pair[C * C];
    __shared__ float s_sim[C];
    const int tid = threadIdx.x;

    if (tid < C) s_cntf[tid] = (float)wsi[OFF_CNT + tid];
    __syncthreads();
    for (int i = tid; i < C * 256; i += 512) {
        int c = i >> 8, d = i & 255;
        float icnt = 1.f / fmaxf(s_cntf[c], 1.f);
        s_cen[c * 260 + d] = (float)wsi[OFF_S + i] * IS_S * icnt;
        s_u[c * 260 + d]   = (float)wsi[OFF_U + i] * IS_U;
    }
    __syncthreads();
    if (tid < C) {
        float nsq = 0.f;
        for (int d = 0; d < D_DIM; ++d) {
            float x = s_cen[tid * 260 + d];
            nsq += x * x;
        }
        s_nc[tid] = sqrtf(nsq);
    }
    __syncthreads();
    if (tid < C * C) {
        int i = tid / C, j = tid % C;
        const float4* ci = (const float4*)&s_cen[i * 260];
        const float4* cj = (const float4*)&s_cen[j * 260];
        float dot = 0.f;
        #pragma unroll 8
        for (int k = 0; k < 64; ++k) {
            float4 a = ci[k], bb = cj[k];
            dot += a.x * bb.x + a.y * bb.y + a.z * bb.z + a.w * bb.w;
        }
        float S = dot / fmaxf(s_nc[i] * s_nc[j], EPS);
        s_pair[tid] = (i == j) ? (1.f - S) : fmaxf(S, 0.f);
    } else if (tid >= 384 && tid < 384 + C) {
        int i = tid - 384;
        const float4* ci = (const float4*)&s_cen[i * 260];
        const float4* ui = (const float4*)&s_u[i * 260];
        float dot = 0.f;
        #pragma unroll 8
        for (int k = 0; k < 64; ++k) {
            float4 a = ci[k], bb = ui[k];
            dot += a.x * bb.x + a.y * bb.y + a.z * bb.z + a.w * bb.w;
        }
        s_sim[i] = (s_cntf[i] > 0.f)
                 ? (1.f - dot / fmaxf(s_nc[i] * s_cntf[i], EPS)) : 0.f;
    }
    __syncthreads();
    if (tid < C) {
        float row = 0.f;
        for (int j = 0; j < C; ++j) row += s_pair[tid * C + j];
        s_pair[tid * C] = (s_cntf[tid] > 0.f) ? (row * (1.f / (float)C)) : 0.f;
    }
    __syncthreads();
    if (tid == 0) {
        float tot = 0.f;
        for (int i = 0; i < C; ++i) tot += s_pair[i * C] + s_sim[i];
        out[0] = tot;
    }
}

extern "C" void kernel_launch(void* const* d_in, const int* in_sizes, int n_in,
                              void* d_out, int out_size, void* d_ws, size_t ws_size,
                              hipStream_t stream) {
    const float* in  = (const float*)d_in[0];
    const int*   tgt = (const int*)d_in[1];
    float* out = (float*)d_out;
    int*   wsi = (int*)d_ws;

    k0_zero<<<39, 256, 0, stream>>>(wsi);
    kA_nf<<<512, 256, 0, stream>>>(in, wsi);
    kB_accu<<<dim3(256, 4), 256, 0, stream>>>(in, tgt, wsi);
    k1b_reduce<<<dim3(3, 32), 256, 0, stream>>>(wsi);
    k2_final<<<1, 512, 0, stream>>>(wsi, out);
}

// Round 8
// 229.634 us; speedup vs baseline: 1.0505x; 1.0505x over previous
//
#include <hip/hip_runtime.h>
#include <math.h>

#define D_DIM 256
#define HW 16384
#define C 19
#define EPS 1e-8f

#define S_SC 1048576.0f        // 2^20 fixed point, |class sum| < ~2000 -> safe in int32
#define IS_S (1.0f/1048576.0f)
#define U_SC 16777216.0f       // 2^24 fixed point, |unit sum| < ~30
#define IS_U (1.0f/16777216.0f)

// ws layout (4-byte words)
#define OFF_S      0           // int[4864]  final S (plain-stored by k1b)
#define OFF_U      4864        // int[4864]  final U
#define OFF_CNT    9728        // int[19]    counts (+13 pad)
#define OFF_IO     9760        // float[131072] U_SC/||f_px||
#define OFF_PNF    140832      // float[512][8256] nf slab-partials (padded stride: non-pow2)
#define PNF_STRIDE 8256
#define OFF_PS     4367904     // int[512][152] S partial rows
#define OFF_PU     4445728     // int[512][152] U partial rows

// ---------- kA: sequential stream -> nf partials + class-sum partials ----------
// grid 512 = (b<8) x (slab s<32: 8 d's) x (half h<2: 8192 hw). 256 thr.
// Thread t owns hw = h*8192 + t*4 + it*1024 (it<8); streams its 8 d's sequentially.
__global__ __launch_bounds__(256) void kA_stream(const float* __restrict__ in,
                                                 const int* __restrict__ tgt,
                                                 int* __restrict__ wsi) {
    __shared__ int sS[8 * 161];   // 8 copies, stride 161: copy c, label l -> bank (c+20d+l)%32
    const int tid = threadIdx.x;
    const int bid = blockIdx.x;
    const int b = bid >> 6, s = (bid >> 1) & 31, h = bid & 1;
    const int copy = tid & 7;
    for (int i = tid; i < 8 * 161; i += 256) sS[i] = 0;
    __syncthreads();

    const int hwb = (h << 13) + (tid << 2);
    const int pb  = (b << 14) + hwb;
    int4 lab[8];
    #pragma unroll
    for (int it = 0; it < 8; ++it) lab[it] = *(const int4*)(tgt + pb + (it << 10));

    const float* base = in + (((size_t)((b << 8) + (s << 3))) << 14) + hwb;
    float4 nf[8];
    #pragma unroll
    for (int it = 0; it < 8; ++it) nf[it] = make_float4(0.f, 0.f, 0.f, 0.f);

    #pragma unroll
    for (int d = 0; d < 8; ++d) {
        float4 v[8];
        #pragma unroll
        for (int it = 0; it < 8; ++it)
            v[it] = *(const float4*)(base + ((size_t)d << 14) + (it << 10));
        const int sb = copy * 161 + d * 20;
        #pragma unroll
        for (int it = 0; it < 8; ++it) {
            nf[it].x += v[it].x * v[it].x; nf[it].y += v[it].y * v[it].y;
            nf[it].z += v[it].z * v[it].z; nf[it].w += v[it].w * v[it].w;
            atomicAdd(&sS[sb + lab[it].x], __float2int_rn(v[it].x * S_SC));
            atomicAdd(&sS[sb + lab[it].y], __float2int_rn(v[it].y * S_SC));
            atomicAdd(&sS[sb + lab[it].z], __float2int_rn(v[it].z * S_SC));
            atomicAdd(&sS[sb + lab[it].w], __float2int_rn(v[it].w * S_SC));
        }
    }

    // nf slab-partial writeout (coalesced float4, padded row stride)
    float* pnf = (float*)wsi + OFF_PNF
               + (size_t)(((b << 1) + h) * 32 + s) * PNF_STRIDE;
    #pragma unroll
    for (int it = 0; it < 8; ++it)
        *(float4*)(pnf + (it << 10) + (tid << 2)) = nf[it];

    __syncthreads();
    if (tid < 152) {                          // merge 8 copies -> partial row
        const int d = tid / 19, l = tid - d * 19;
        int acc = 0;
        #pragma unroll
        for (int c = 0; c < 8; ++c) acc += sS[c * 161 + d * 20 + l];
        wsi[OFF_PS + bid * 152 + tid] = acc;
    }
}

// ---------- kA2: combine 32 slab-partials -> io = U_SC * rsqrt(nf); zero CNT ----------
// grid 128 = (b<8) x (h<2) x (chunk<8 of 1024 px). 256 thr, float4/thread.
__global__ __launch_bounds__(256) void kA2_io(int* __restrict__ wsi) {
    float* wsf = (float*)wsi;
    const int j = blockIdx.x, tid = threadIdx.x;
    const int b = j >> 4, h = (j >> 3) & 1, ch = j & 7;
    const float* pn = wsf + OFF_PNF + (size_t)((b << 1) + h) * 32 * PNF_STRIDE
                    + (ch << 10) + (tid << 2);
    float4 acc = {0.f, 0.f, 0.f, 0.f};
    #pragma unroll 8
    for (int s = 0; s < 32; ++s) {
        float4 v = *(const float4*)(pn + (size_t)s * PNF_STRIDE);
        acc.x += v.x; acc.y += v.y; acc.z += v.z; acc.w += v.w;
    }
    float4 io;
    io.x = acc.x > 0.f ? U_SC * rsqrtf(acc.x) : 0.f;
    io.y = acc.y > 0.f ? U_SC * rsqrtf(acc.y) : 0.f;
    io.z = acc.z > 0.f ? U_SC * rsqrtf(acc.z) : 0.f;
    io.w = acc.w > 0.f ? U_SC * rsqrtf(acc.w) : 0.f;
    *(float4*)(wsf + OFF_IO + (b << 14) + (h << 13) + (ch << 10) + (tid << 2)) = io;
    if (j == 0 && tid < 32) wsi[OFF_CNT + tid] = 0;   // before kB's count atomics
}

// ---------- kB: second sequential sweep (L3-hot) -> U partials + counts ----------
__global__ __launch_bounds__(256) void kB_stream(const float* __restrict__ in,
                                                 const int* __restrict__ tgt,
                                                 int* __restrict__ wsi) {
    __shared__ int sU[8 * 161];
    __shared__ int sH[8 * 21];
    const int tid = threadIdx.x;
    const int bid = blockIdx.x;
    const int b = bid >> 6, s = (bid >> 1) & 31, h = bid & 1;
    const int copy = tid & 7;
    for (int i = tid; i < 8 * 161; i += 256) sU[i] = 0;
    if (tid < 8 * 21) sH[tid] = 0;
    __syncthreads();

    const int hwb = (h << 13) + (tid << 2);
    const int pb  = (b << 14) + hwb;
    const float* iof = (const float*)wsi + OFF_IO;
    int4   lab[8];
    float4 io4[8];
    #pragma unroll
    for (int it = 0; it < 8; ++it) {
        lab[it] = *(const int4*)(tgt + pb + (it << 10));
        io4[it] = *(const float4*)(iof + pb + (it << 10));
    }
    if (s == 0) {                              // each px counted exactly once
        #pragma unroll
        for (int it = 0; it < 8; ++it) {
            atomicAdd(&sH[copy * 21 + lab[it].x], 1);
            atomicAdd(&sH[copy * 21 + lab[it].y], 1);
            atomicAdd(&sH[copy * 21 + lab[it].z], 1);
            atomicAdd(&sH[copy * 21 + lab[it].w], 1);
        }
    }

    const float* base = in + (((size_t)((b << 8) + (s << 3))) << 14) + hwb;
    #pragma unroll
    for (int d = 0; d < 8; ++d) {
        float4 v[8];
        #pragma unroll
        for (int it = 0; it < 8; ++it)
            v[it] = *(const float4*)(base + ((size_t)d << 14) + (it << 10));
        const int sb = copy * 161 + d * 20;
        #pragma unroll
        for (int it = 0; it < 8; ++it) {
            atomicAdd(&sU[sb + lab[it].x], __float2int_rn(v[it].x * io4[it].x));
            atomicAdd(&sU[sb + lab[it].y], __float2int_rn(v[it].y * io4[it].y));
            atomicAdd(&sU[sb + lab[it].z], __float2int_rn(v[it].z * io4[it].z));
            atomicAdd(&sU[sb + lab[it].w], __float2int_rn(v[it].w * io4[it].w));
        }
    }
    __syncthreads();
    if (tid < 152) {
        const int d = tid / 19, l = tid - d * 19;
        int acc = 0;
        #pragma unroll
        for (int c = 0; c < 8; ++c) acc += sU[c * 161 + d * 20 + l];
        wsi[OFF_PU + bid * 152 + tid] = acc;
    }
    if (s == 0 && tid < C) {
        int t = 0;
        #pragma unroll
        for (int c = 0; c < 8; ++c) t += sH[c * 21 + tid];
        atomicAdd(&wsi[OFF_CNT + tid], t);
    }
}

// ---------- k1b: merge 16 (b,h)-rows per slab -> final S/U, plain stores ----------
// grid 64: a = array (S/U), s = slab.
__global__ __launch_bounds__(256) void k1b_merge(int* __restrict__ wsi) {
    const int a = blockIdx.x >> 5, s = blockIdx.x & 31;
    const int tid = threadIdx.x;
    if (tid >= 152) return;
    const int* src = wsi + (a ? OFF_PU : OFF_PS);
    int acc = 0;
    #pragma unroll
    for (int r = 0; r < 16; ++r) {            // row = b*64 + s*2 + h
        const int row = ((r >> 1) << 6) + (s << 1) + (r & 1);
        acc += src[row * 152 + tid];
    }
    const int d = tid / 19, l = tid - (tid / 19) * 19;
    wsi[(a ? OFF_U : OFF_S) + l * D_DIM + (s << 3) + d] = acc;
}

// ---------- k2: centers, norms, Gram/diff, sim, final (1 block; validated) ----------
__global__ __launch_bounds__(512) void k2_final(const int* __restrict__ wsi,
                                                float* __restrict__ out) {
    __shared__ __align__(16) float s_cen[C * 260];
    __shared__ __align__(16) float s_u[C * 260];
    __shared__ float s_nc[C];
    __shared__ float s_cntf[C];
    __shared__ float s_pair[C * C];
    __shared__ float s_sim[C];
    const int tid = threadIdx.x;

    if (tid < C) s_cntf[tid] = (float)wsi[OFF_CNT + tid];
    __syncthreads();
    for (int i = tid; i < C * 256; i += 512) {
        int c = i >> 8, d = i & 255;
        float icnt = 1.f / fmaxf(s_cntf[c], 1.f);
        s_cen[c * 260 + d] = (float)wsi[OFF_S + i] * IS_S * icnt;
        s_u[c * 260 + d]   = (float)wsi[OFF_U + i] * IS_U;
    }
    __syncthreads();
    if (tid < C) {
        float nsq = 0.f;
        for (int d = 0; d < D_DIM; ++d) {
            float x = s_cen[tid * 260 + d];
            nsq += x * x;
        }
        s_nc[tid] = sqrtf(nsq);
    }
    __syncthreads();
    if (tid < C * C) {
        int i = tid / C, j = tid % C;
        const float4* ci = (const float4*)&s_cen[i * 260];
        const float4* cj = (const float4*)&s_cen[j * 260];
        float dot = 0.f;
        #pragma unroll 8
        for (int k = 0; k < 64; ++k) {
            float4 a = ci[k], bb = cj[k];
            dot += a.x * bb.x + a.y * bb.y + a.z * bb.z + a.w * bb.w;
        }
        float S = dot / fmaxf(s_nc[i] * s_nc[j], EPS);
        s_pair[tid] = (i == j) ? (1.f - S) : fmaxf(S, 0.f);
    } else if (tid >= 384 && tid < 384 + C) {
        int i = tid - 384;
        const float4* ci = (const float4*)&s_cen[i * 260];
        const float4* ui = (const float4*)&s_u[i * 260];
        float dot = 0.f;
        #pragma unroll 8
        for (int k = 0; k < 64; ++k) {
            float4 a = ci[k], bb = ui[k];
            dot += a.x * bb.x + a.y * bb.y + a.z * bb.z + a.w * bb.w;
        }
        s_sim[i] = (s_cntf[i] > 0.f)
                 ? (1.f - dot / fmaxf(s_nc[i] * s_cntf[i], EPS)) : 0.f;
    }
    __syncthreads();
    if (tid < C) {
        float row = 0.f;
        for (int j = 0; j < C; ++j) row += s_pair[tid * C + j];
        s_pair[tid * C] = (s_cntf[tid] > 0.f) ? (row * (1.f / (float)C)) : 0.f;
    }
    __syncthreads();
    if (tid == 0) {
        float tot = 0.f;
        for (int i = 0; i < C; ++i) tot += s_pair[i * C] + s_sim[i];
        out[0] = tot;
    }
}

extern "C" void kernel_launch(void* const* d_in, const int* in_sizes, int n_in,
                              void* d_out, int out_size, void* d_ws, size_t ws_size,
                              hipStream_t stream) {
    const float* in  = (const float*)d_in[0];
    const int*   tgt = (const int*)d_in[1];
    float* out = (float*)d_out;
    int*   wsi = (int*)d_ws;

    kA_stream<<<512, 256, 0, stream>>>(in, tgt, wsi);
    kA2_io<<<128, 256, 0, stream>>>(wsi);
    kB_stream<<<512, 256, 0, stream>>>(in, tgt, wsi);
    k1b_merge<<<64, 256, 0, stream>>>(wsi);
    k2_final<<<1, 512, 0, stream>>>(wsi, out);
}